// Round 9
// baseline (247.763 us; speedup 1.0000x reference)
//
#include <hip/hip_runtime.h>
#include <hip/hip_bf16.h>
#include <stdint.h>

#define ALPHA 1.0f

typedef __attribute__((ext_vector_type(8))) short bf16x8;
typedef __attribute__((ext_vector_type(4))) float f32x4;
typedef unsigned short ushort_t;

__device__ __forceinline__ unsigned short f32_to_bf16_rne(float f) {
    union { float f; unsigned int u; } v; v.f = f;
    unsigned int u = v.u;
    unsigned int r = u + 0x7FFFu + ((u >> 16) & 1u);
    return (unsigned short)(r >> 16);
}

__device__ __forceinline__ unsigned int cvt_pk_bf16(float lo, float hi) {
    unsigned int r;
    asm("v_cvt_pk_bf16_f32 %0, %1, %2" : "=v"(r) : "v"(lo), "v"(hi));
    return r;
}

__device__ __forceinline__ void async_copy16(const void* g, void* l) {
    __builtin_amdgcn_global_load_lds(
        (const __attribute__((address_space(1))) void*)g,
        (__attribute__((address_space(3))) void*)l, 16, 0, 0);
}

// ---------------------------------------------------------------------------
// Fused W_eff: weff[o][i] = W[o][i] + ALPHA * sum_r fac[o][r] * t1[r][i]
template <bool BF16OUT>
__global__ __launch_bounds__(256)
void weff_fused_kernel(const float* __restrict__ W,
                       const float* __restrict__ lora_down,
                       const float* __restrict__ lora_up,
                       const float* __restrict__ down_aux,
                       const float* __restrict__ up_aux,
                       void* __restrict__ weff) {
    int o = blockIdx.x;
    int i0 = threadIdx.x * 4;

    float fac[4] = {0.f, 0.f, 0.f, 0.f};
    for (int u = 0; u < 50; ++u) {
        float ua = up_aux[o * 50 + u] * ALPHA;
#pragma unroll
        for (int r = 0; r < 4; ++r) fac[r] += ua * lora_up[u * 4 + r];
    }

    float4 t1[4];
#pragma unroll
    for (int r = 0; r < 4; ++r) t1[r] = make_float4(0.f, 0.f, 0.f, 0.f);
    for (int d = 0; d < 100; ++d) {
        float4 da = *(const float4*)(down_aux + d * 1024 + i0);
#pragma unroll
        for (int r = 0; r < 4; ++r) {
            float ld = lora_down[r * 100 + d];
            t1[r].x += ld * da.x; t1[r].y += ld * da.y;
            t1[r].z += ld * da.z; t1[r].w += ld * da.w;
        }
    }

    float4 acc = *(const float4*)(W + (long)o * 1024 + i0);
#pragma unroll
    for (int r = 0; r < 4; ++r) {
        acc.x += fac[r] * t1[r].x; acc.y += fac[r] * t1[r].y;
        acc.z += fac[r] * t1[r].z; acc.w += fac[r] * t1[r].w;
    }

    if (BF16OUT) {
        ushort4 rr;
        rr.x = f32_to_bf16_rne(acc.x); rr.y = f32_to_bf16_rne(acc.y);
        rr.z = f32_to_bf16_rne(acc.z); rr.w = f32_to_bf16_rne(acc.w);
        *(ushort4*)((ushort_t*)weff + (long)o * 1024 + i0) = rr;
    } else {
        *(float4*)((float*)weff + (long)o * 1024 + i0) = acc;
    }
}

// ---------------------------------------------------------------------------
// Fully-fused GEMM: C = cvt_bf16(A_f32[M][K]) * Bt_bf16[N][K]^T + bias
// 256x256x64 tile, 8 waves (2Mx4N), per-wave 128x64 = acc[8][4] f32x4 (AGPR).
// 2-barrier/K-tile counted-sync schedule with FULL-COVER A staging:
//   A(j+2) f32 loads (both halves, 32 VGPR vP/vQ) issued at iter j's B2,
//   consumed at iter j+1 postQ0 / postQ2 -> >= 1 full iteration of HBM cover.
//   Counted waits (compiler-derived from queue order):
//     postQ0 cvt(vP): vmcnt(8);  postQ2 cvt(vQ): vmcnt(4);
//     gate: vmcnt(12) lgkmcnt(0)  -- 12 = A(j+2) 8 + B(j+2) 4 stay in flight.
//   bH fragment reads deferred to post-Q0 (peak-reg offset for vP/vQ).
//   B: glds bf16, pre-swizzled global source (L2-resident weff).
#define BMM 256
#define BNN 256
#define BKK 64

__global__ __launch_bounds__(512, 2)
void gemm_fused_kernel(const float* __restrict__ A,
                       const ushort_t* __restrict__ Bt,
                       const float* __restrict__ bias,
                       float* __restrict__ C, int M, int N, int K) {
    __shared__ __align__(16) ushort_t Ab[2][BMM * BKK];  // 2 x 32 KB
    __shared__ __align__(16) ushort_t Bb[2][BNN * BKK];  // 2 x 32 KB

    int nTilesN = N / BNN;  // 4
    int nwg = gridDim.x;
    int bid = blockIdx.x;
    int swz = bid;
    if ((nwg & 7) == 0) {   // grid = 1024 -> bijective XCD swizzle
        int cpx = nwg >> 3;
        swz = (bid & 7) * cpx + (bid >> 3);
    }
    int tm = swz / nTilesN;
    int tn = swz % nTilesN;
    const long rowA0 = (long)tm * BMM;
    const long colB0 = (long)tn * BNN;

    int tid = threadIdx.x;
    int lane = tid & 63;
    int wave = tid >> 6;     // 0..7
    int wr = wave >> 2;      // 0..1  (M)
    int wc = wave & 3;       // 0..3  (N)

    // ---- A staging map (per half-tile: 128 rows x 64 k f32) ----
    int amrow[2], amcol[2], amlds[2];
#pragma unroll
    for (int q = 0; q < 2; ++q) {
        int p = q * 512 + tid;
        amrow[q] = p >> 3;
        amcol[q] = p & 7;
        amlds[q] = amcol[q] ^ (amrow[q] & 7);
    }

    // ---- B staging map (glds, pre-swizzled source) ----
    int prow[2], pcg[2];
#pragma unroll
    for (int q = 0; q < 2; ++q) {
        int pc = q * 512 + tid;
        prow[q] = pc >> 3;
        pcg[q] = (pc & 7) ^ (prow[q] & 7);
    }

    // fragment map
    int fr = lane & 15;
    int h4 = lane >> 4;
    int s7 = fr & 7;
    int aoff = (wr * 128 + fr) * 64;
    int boff = (wc * 64 + fr) * 64;
    int ck[2] = { (h4 ^ s7) * 8, ((4 + h4) ^ s7) * 8 };

    f32x4 acc[8][4];
#pragma unroll
    for (int m = 0; m < 8; ++m)
#pragma unroll
        for (int n = 0; n < 4; ++n) acc[m][n] = (f32x4)(0.0f);

    const int nIter = K / BKK;  // 16

    // double-buffered A staging regs: vP = half0, vQ = half1 (32 VGPR)
    float4 vP0[2], vP1[2], vQ0[2], vQ1[2];

    auto loadAh0 = [&](int kt) {
        const float* src = A + rowA0 * (long)K + kt * BKK;
#pragma unroll
        for (int q = 0; q < 2; ++q) {
            const float* gp = src + (long)amrow[q] * K + amcol[q] * 8;
            vP0[q] = ((const float4*)gp)[0];
            vP1[q] = ((const float4*)gp)[1];
        }
    };
    auto loadAh1 = [&](int kt) {
        const float* src = A + (rowA0 + 128) * (long)K + kt * BKK;
#pragma unroll
        for (int q = 0; q < 2; ++q) {
            const float* gp = src + (long)amrow[q] * K + amcol[q] * 8;
            vQ0[q] = ((const float4*)gp)[0];
            vQ1[q] = ((const float4*)gp)[1];
        }
    };
    auto writeAh0 = [&](int bufsel) {
        ushort_t* dst = &Ab[bufsel][0];
#pragma unroll
        for (int q = 0; q < 2; ++q) {
            uint4 w;
            w.x = cvt_pk_bf16(vP0[q].x, vP0[q].y);
            w.y = cvt_pk_bf16(vP0[q].z, vP0[q].w);
            w.z = cvt_pk_bf16(vP1[q].x, vP1[q].y);
            w.w = cvt_pk_bf16(vP1[q].z, vP1[q].w);
            *(uint4*)(dst + amrow[q] * 64 + amlds[q] * 8) = w;
        }
    };
    auto writeAh1 = [&](int bufsel) {
        ushort_t* dst = &Ab[bufsel][8192];
#pragma unroll
        for (int q = 0; q < 2; ++q) {
            uint4 w;
            w.x = cvt_pk_bf16(vQ0[q].x, vQ0[q].y);
            w.y = cvt_pk_bf16(vQ0[q].z, vQ0[q].w);
            w.z = cvt_pk_bf16(vQ1[q].x, vQ1[q].y);
            w.w = cvt_pk_bf16(vQ1[q].z, vQ1[q].w);
            *(uint4*)(dst + amrow[q] * 64 + amlds[q] * 8) = w;
        }
    };
    auto stageB = [&](int kt, int h, int bufsel) {
        const ushort_t* src = Bt + (colB0 + h * 128) * (long)K + kt * BKK;
        ushort_t* dst = &Bb[bufsel][h * 8192 + wave * 512];
#pragma unroll
        for (int q = 0; q < 2; ++q)
            async_copy16(src + (long)prow[q] * K + pcg[q] * 8, dst + q * 4096);
    };

    // ---------------- prologue ----------------
    loadAh0(0); loadAh1(0);               // A(0): 8 loads
    stageB(0, 0, 0); stageB(0, 1, 0);     // B(0): 4 glds
    writeAh0(0);                          // waits vP (vmcnt(8)): HBM once
    writeAh1(0);                          // waits vQ (vmcnt(4))
    loadAh0(1); loadAh1(1);               // A(1): 8 loads
    stageB(1, 0, 1); stageB(1, 1, 1);     // B(1): 4 glds
    asm volatile("s_waitcnt vmcnt(12) lgkmcnt(0)" ::: "memory");  // B(0) landed
    __builtin_amdgcn_s_barrier();

#pragma unroll 1
    for (int j = 0; j < nIter; ++j) {
        int c = j & 1, o = c ^ 1;
        const ushort_t* Ac = &Ab[c][0];
        const ushort_t* Bc = &Bb[c][0];
        bool stage1 = (j + 1 < nIter);   // vP/vQ hold A(j+1)
        bool stage2 = (j + 2 < nIter);   // issue A(j+2)/B(j+2)

        // ---- fragment reads: aL, bL (bH deferred, aH after Q1) ----
        bf16x8 aL[4][2], aH[4][2], bL[2][2], bH[2][2];
#pragma unroll
        for (int m = 0; m < 4; ++m)
#pragma unroll
            for (int kk = 0; kk < 2; ++kk)
                aL[m][kk] = *(const bf16x8*)&Ac[aoff + m * 1024 + ck[kk]];
#pragma unroll
        for (int n = 0; n < 2; ++n)
#pragma unroll
            for (int kk = 0; kk < 2; ++kk)
                bL[n][kk] = *(const bf16x8*)&Bc[boff + n * 1024 + ck[kk]];

        // ---- Q0: aL x bL ----
        __builtin_amdgcn_s_setprio(1);
#pragma unroll
        for (int m = 0; m < 4; ++m)
#pragma unroll
            for (int n = 0; n < 2; ++n)
#pragma unroll
                for (int kk = 0; kk < 2; ++kk)
                    acc[m][n] = __builtin_amdgcn_mfma_f32_16x16x32_bf16(
                        aL[m][kk], bL[n][kk], acc[m][n], 0, 0, 0);
        __builtin_amdgcn_s_setprio(0);

        // cvt+write A(j+1)h0 -> buf o  (vP arrived: issued a full iter ago)
        if (stage1) writeAh0(o);

        // bH fragment reads (stream under the cvt/Q1 boundary)
#pragma unroll
        for (int n = 0; n < 2; ++n)
#pragma unroll
            for (int kk = 0; kk < 2; ++kk)
                bH[n][kk] = *(const bf16x8*)&Bc[boff + (n + 2) * 1024 + ck[kk]];

        // ---- Q1: aL x bH ----
        __builtin_amdgcn_s_setprio(1);
#pragma unroll
        for (int m = 0; m < 4; ++m)
#pragma unroll
            for (int n = 0; n < 2; ++n)
#pragma unroll
                for (int kk = 0; kk < 2; ++kk)
                    acc[m][n + 2] = __builtin_amdgcn_mfma_f32_16x16x32_bf16(
                        aL[m][kk], bH[n][kk], acc[m][n + 2], 0, 0, 0);
        __builtin_amdgcn_s_setprio(0);

        // aH fragment reads
#pragma unroll
        for (int m = 0; m < 4; ++m)
#pragma unroll
            for (int kk = 0; kk < 2; ++kk)
                aH[m][kk] = *(const bf16x8*)&Ac[aoff + (m + 4) * 1024 + ck[kk]];

        // ---- Q2: aH x bH ----
        __builtin_amdgcn_s_setprio(1);
#pragma unroll
        for (int m = 0; m < 4; ++m)
#pragma unroll
            for (int n = 0; n < 2; ++n)
#pragma unroll
                for (int kk = 0; kk < 2; ++kk)
                    acc[m + 4][n + 2] = __builtin_amdgcn_mfma_f32_16x16x32_bf16(
                        aH[m][kk], bH[n][kk], acc[m + 4][n + 2], 0, 0, 0);
        __builtin_amdgcn_s_setprio(0);

        // cvt+write A(j+1)h1 -> buf o  (vQ arrived: full-iter cover)
        if (stage1) writeAh1(o);

        // all waves' reads of buf c retired (Q2 consumed the last ones)
        __builtin_amdgcn_s_barrier();            // B2

        // issue next-generation VMEM: A(j+2) regs + B(j+2) glds -> buf c
        if (stage2) {
            loadAh0(j + 2); loadAh1(j + 2);
            stageB(j + 2, 0, c); stageB(j + 2, 1, c);
        }

        // ---- Q3: aH x bL (pure-reg; overlaps the 12 in-flight VMEM) ----
        __builtin_amdgcn_s_setprio(1);
#pragma unroll
        for (int m = 0; m < 4; ++m)
#pragma unroll
            for (int n = 0; n < 2; ++n)
#pragma unroll
                for (int kk = 0; kk < 2; ++kk)
                    acc[m + 4][n] = __builtin_amdgcn_mfma_f32_16x16x32_bf16(
                        aH[m][kk], bL[n][kk], acc[m + 4][n], 0, 0, 0);
        __builtin_amdgcn_s_setprio(0);

        // gate: B(j+1) landed; A(j+2)+B(j+2) (12) stay in flight
        if (stage2) {
            asm volatile("s_waitcnt vmcnt(12) lgkmcnt(0)" ::: "memory");
        } else {
            asm volatile("s_waitcnt vmcnt(0) lgkmcnt(0)" ::: "memory");
        }
        __builtin_amdgcn_s_barrier();            // B0
    }

    // ---- epilogue: C = acc + bias ----
    int ccol = lane & 15;
    int crow = (lane >> 4) * 4;
#pragma unroll
    for (int m = 0; m < 8; ++m) {
        long grow = rowA0 + wr * 128 + m * 16 + crow;
#pragma unroll
        for (int n = 0; n < 4; ++n) {
            long gcol = colB0 + wc * 64 + n * 16 + ccol;
            float bb = bias[gcol];
#pragma unroll
            for (int r = 0; r < 4; ++r) {
                C[(grow + r) * N + gcol] = acc[m][n][r] + bb;
            }
        }
    }
}

// ---------------------------------------------------------------------------
// Fallback: plain f32 tiled GEMM (used only if ws too small for bf16 path)
__global__ __launch_bounds__(256)
void gemm_f32_fallback(const float* __restrict__ A, const float* __restrict__ Bt,
                       const float* __restrict__ bias, float* __restrict__ C,
                       int M, int N, int K) {
    __shared__ float As[64][17];
    __shared__ float Bs[64][17];
    int tilesN = N / 64;
    int tm = blockIdx.x / tilesN;
    int tn = blockIdx.x % tilesN;
    int tid = threadIdx.x;
    int tr = tid / 16, tc = tid % 16;
    float acc[4][4] = {};
    for (int k0 = 0; k0 < K; k0 += 16) {
        for (int t = tid; t < 64 * 16; t += 256) {
            int r = t / 16, c = t % 16;
            As[r][c] = A[((long)tm * 64 + r) * K + k0 + c];
            Bs[r][c] = Bt[((long)tn * 64 + r) * K + k0 + c];
        }
        __syncthreads();
#pragma unroll
        for (int kk = 0; kk < 16; ++kk) {
            float av[4], bv[4];
#pragma unroll
            for (int i = 0; i < 4; ++i) av[i] = As[tr * 4 + i][kk];
#pragma unroll
            for (int j = 0; j < 4; ++j) bv[j] = Bs[tc * 4 + j][kk];
#pragma unroll
            for (int i = 0; i < 4; ++i)
#pragma unroll
                for (int j = 0; j < 4; ++j) acc[i][j] += av[i] * bv[j];
        }
        __syncthreads();
    }
#pragma unroll
    for (int i = 0; i < 4; ++i) {
        long row = (long)tm * 64 + tr * 4 + i;
#pragma unroll
        for (int j = 0; j < 4; ++j) {
            long col = (long)tn * 64 + tc * 4 + j;
            C[row * N + col] = acc[i][j] + bias[col];
        }
    }
}

// ---------------------------------------------------------------------------
extern "C" void kernel_launch(void* const* d_in, const int* in_sizes, int n_in,
                              void* d_out, int out_size, void* d_ws, size_t ws_size,
                              hipStream_t stream) {
    const float* hs        = (const float*)d_in[0];
    const float* W         = (const float*)d_in[1];
    const float* b         = (const float*)d_in[2];
    const float* lora_down = (const float*)d_in[3];
    const float* lora_up   = (const float*)d_in[4];
    const float* down_aux  = (const float*)d_in[5];
    const float* up_aux    = (const float*)d_in[6];
    float* out = (float*)d_out;

    const int K = 1024;   // IN
    const int N = 1024;   // OUT
    const int M = in_sizes[0] / K;  // B*S = 65536

    char* ws = (char*)d_ws;
    const size_t NEED_FAST = 2 * 1024 * 1024;   // weff bf16 only

    if (ws_size >= NEED_FAST && (M % BMM) == 0) {
        ushort_t* weff = (ushort_t*)ws;
        weff_fused_kernel<true><<<N, 256, 0, stream>>>(W, lora_down, lora_up,
                                                       down_aux, up_aux, weff);
        int grid = (M / BMM) * (N / BNN);   // 1024
        gemm_fused_kernel<<<grid, 512, 0, stream>>>(hs, weff, b, out, M, N, K);
    } else {
        float* weff = (float*)ws;  // 4MB
        weff_fused_kernel<false><<<N, 256, 0, stream>>>(W, lora_down, lora_up,
                                                        down_aux, up_aux, weff);
        int grid = (M / 64) * (N / 64);
        gemm_f32_fallback<<<grid, 256, 0, stream>>>(hs, weff, b, out, M, N, K);
    }
}